// Round 9
// baseline (675.187 us; speedup 1.0000x reference)
//
#include <hip/hip_runtime.h>

#define N_NODES 100000
#define N_EDGES 1600000
#define D 128
#define NLAYERS 4
#define NGRAPH 100
#define NOUT 10
#define BN_EPS 1e-5f

#define SORT_B 391     // pass-1 blocks: 391 * 4096 >= E; also 391 bins of dst>>8
#define BIN_CAP 6144   // max edges per high-bit bin

#define DH_NR 7        // deg-hist node ranges of 16384
#define DH_SL 32       // deg-hist edge slices
#define DH_RANGE 16384
#define DH_PAD (DH_NR * DH_RANGE)   // 114688

#define FUSED_BLOCKS ((N_NODES + 63) / 64)   // 1563

typedef __attribute__((ext_vector_type(8))) short bf16x8;
typedef __attribute__((ext_vector_type(8))) unsigned short u16x8;
typedef __attribute__((ext_vector_type(4))) float f32x4;

static __device__ __forceinline__ unsigned short f2bf(float f) {
    unsigned u = __builtin_bit_cast(unsigned, f);
    unsigned r = (u + 0x7fffu + ((u >> 16) & 1u)) >> 16;
    return (unsigned short)r;
}
static __device__ __forceinline__ float bf2f(unsigned short b) {
    unsigned u = ((unsigned)b) << 16;
    return __builtin_bit_cast(float, u);
}

// ---------------------------------------------------------------- deg_out histogram, zero global atomics
__global__ __launch_bounds__(256) void deg_hist_kernel(const int* __restrict__ src,
                                                       int* __restrict__ partial) {
    __shared__ int hist[DH_RANGE];   // 64 KB
    int t = threadIdx.x;
    int r = blockIdx.x / DH_SL;
    int s = blockIdx.x % DH_SL;
#pragma unroll
    for (int i = 0; i < 16; ++i)
        reinterpret_cast<int4*>(hist)[t + i * 256] = make_int4(0, 0, 0, 0);
    __syncthreads();
    int lo = r * DH_RANGE, hi = lo + DH_RANGE;
    int e0 = s * (N_EDGES / DH_SL);
    for (int i = t; i < (N_EDGES / DH_SL) / 4; i += 256) {
        int4 v = *reinterpret_cast<const int4*>(src + e0 + i * 4);
        if (v.x >= lo && v.x < hi) atomicAdd(&hist[v.x - lo], 1);
        if (v.y >= lo && v.y < hi) atomicAdd(&hist[v.y - lo], 1);
        if (v.z >= lo && v.z < hi) atomicAdd(&hist[v.z - lo], 1);
        if (v.w >= lo && v.w < hi) atomicAdd(&hist[v.w - lo], 1);
    }
    __syncthreads();
    int4* dst4 = reinterpret_cast<int4*>(partial + (size_t)s * DH_PAD + lo);
#pragma unroll
    for (int i = 0; i < 16; ++i)
        dst4[t + i * 256] = reinterpret_cast<int4*>(hist)[t + i * 256];
}

// ---------------------------------------------------------------- pass 1 hist (512 bins by dst>>8)
__global__ __launch_bounds__(256) void hist1_kernel(const int* __restrict__ dst,
                                                    int* __restrict__ ph) {
    __shared__ int h[512];
    int t = threadIdx.x;
    h[t] = 0; h[t + 256] = 0;
    __syncthreads();
    int base = blockIdx.x * 4096;
#pragma unroll
    for (int i = 0; i < 4; ++i) {
        int e = base + (t + i * 256) * 4;
        if (e + 3 < N_EDGES) {
            int4 v = *reinterpret_cast<const int4*>(dst + e);
            atomicAdd(&h[v.x >> 8], 1);
            atomicAdd(&h[v.y >> 8], 1);
            atomicAdd(&h[v.z >> 8], 1);
            atomicAdd(&h[v.w >> 8], 1);
        } else {
            for (int q = 0; q < 4; ++q)
                if (e + q < N_EDGES) atomicAdd(&h[dst[e + q] >> 8], 1);
        }
    }
    __syncthreads();
    ph[t * SORT_B + blockIdx.x] = h[t];
    ph[(t + 256) * SORT_B + blockIdx.x] = h[t + 256];
}

__global__ __launch_bounds__(256) void place1_kernel(const int* __restrict__ dst,
        const int* __restrict__ src, const int* __restrict__ ph,
        int2* __restrict__ kv1) {
    __shared__ int cur[512];
    int t = threadIdx.x;
    cur[t] = ph[t * SORT_B + blockIdx.x];
    cur[t + 256] = ph[(t + 256) * SORT_B + blockIdx.x];
    __syncthreads();
    int base = blockIdx.x * 4096;
#pragma unroll
    for (int i = 0; i < 16; ++i) {
        int e = base + i * 256 + t;
        if (e < N_EDGES) {
            int k = dst[e];
            int pos = atomicAdd(&cur[k >> 8], 1);
            kv1[pos] = make_int2(k, src[e]);
        }
    }
}

// ---------------------------------------------------------------- pass 2: in-LDS counting sort per bin
__global__ __launch_bounds__(256) void binsort_kernel(const int2* __restrict__ kv1,
        const int* __restrict__ ph, int* __restrict__ col, int* __restrict__ rp) {
    __shared__ int vsh[BIN_CAP];
    __shared__ int osh[BIN_CAP];
    __shared__ unsigned char ksh[BIN_CAP];
    __shared__ int hist[256];
    __shared__ int sc[256];
    __shared__ int cur[256];
    int t = threadIdx.x;
    int b = blockIdx.x;
    int start = ph[b * SORT_B];
    int end = (b == SORT_B - 1) ? N_EDGES : ph[(b + 1) * SORT_B];
    int n = end - start;
    if (n > BIN_CAP) n = BIN_CAP;
    hist[t] = 0;
    __syncthreads();
    for (int i = t; i < n; i += 256) {
        int2 kv = kv1[start + i];
        int d = kv.x & 255;
        ksh[i] = (unsigned char)d;
        vsh[i] = kv.y;
        atomicAdd(&hist[d], 1);
    }
    __syncthreads();
    int hv = hist[t];
    sc[t] = hv;
    __syncthreads();
    for (int off = 1; off < 256; off <<= 1) {
        int x = 0;
        if (t >= off) x = sc[t - off];
        __syncthreads();
        sc[t] += x;
        __syncthreads();
    }
    int pos = sc[t] - hv;
    cur[t] = pos;
    int v = b * 256 + t;
    if (v < N_NODES) rp[v] = start + pos;
    if (b == SORT_B - 1 && t == 0) rp[N_NODES] = N_EDGES;
    __syncthreads();
    for (int i = t; i < n; i += 256) {
        int d = ksh[i];
        int p = atomicAdd(&cur[d], 1);
        osh[p] = vsh[i];
    }
    __syncthreads();
    for (int i = t; i < n; i += 256) col[start + i] = osh[i];
}

// ---------------------------------------------------------------- generalized scan (exclusive)
__global__ void scanA_kernel(int* __restrict__ data, int* __restrict__ blksum, int n) {
    __shared__ int s[256];
    int t = threadIdx.x;
    int base = blockIdx.x * 2048 + t * 8;
    int v[8]; int sum = 0;
#pragma unroll
    for (int j = 0; j < 8; ++j) { v[j] = (base + j < n) ? data[base + j] : 0; sum += v[j]; }
    s[t] = sum;
    __syncthreads();
    for (int off = 1; off < 256; off <<= 1) {
        int x = 0;
        if (t >= off) x = s[t - off];
        __syncthreads();
        s[t] += x;
        __syncthreads();
    }
    int run = s[t] - sum;
#pragma unroll
    for (int j = 0; j < 8; ++j) { if (base + j < n) data[base + j] = run; run += v[j]; }
    if (t == 255) blksum[blockIdx.x] = s[255];
}

__global__ void scanB_kernel(int* __restrict__ blksum, int nb) {
    __shared__ int s[256];
    int t = threadIdx.x;
    int v = (t < nb) ? blksum[t] : 0;
    s[t] = v;
    __syncthreads();
    for (int off = 1; off < 256; off <<= 1) {
        int x = 0;
        if (t >= off) x = s[t - off];
        __syncthreads();
        s[t] += x;
        __syncthreads();
    }
    if (t < nb) blksum[t] = s[t] - v;
}

__global__ void scanC_kernel(int* __restrict__ data, const int* __restrict__ blksum, int n) {
    int i = blockIdx.x * blockDim.x + threadIdx.x;
    if (i < n) data[i] += blksum[i >> 11];
}

// ---------------------------------------------------------------- norms
__global__ void norms_kernel(const int* __restrict__ partial, const int* __restrict__ rp,
                             float* __restrict__ norm_src, float* __restrict__ norm_dst) {
    int v = blockIdx.x * blockDim.x + threadIdx.x;
    if (v < N_NODES) {
        int d = 0;
#pragma unroll
        for (int s = 0; s < DH_SL; ++s) d += partial[(size_t)s * DH_PAD + v];
        norm_src[v] = rsqrtf((float)max(d, 1));
        norm_dst[v] = rsqrtf((float)max(rp[v + 1] - rp[v], 1));
    }
}

// ---------------------------------------------------------------- weight prep (bf16, B^T, XOR-swizzled)
__global__ void wprep_kernel(const float* __restrict__ W, unsigned short* __restrict__ Wt) {
    int i = blockIdx.x * blockDim.x + threadIdx.x;
    if (i >= NLAYERS * D * D) return;
    int l = i >> 14;
    int r = i & (D * D - 1);
    int col = r >> 7;
    int k = r & 127;
    float v = W[(size_t)l * D * D + k * D + col];
    int byteoff = col * 256 + k * 2;
    int swz = byteoff ^ ((col & 7) << 4);
    Wt[(size_t)l * D * D + (swz >> 1)] = f2bf(v);
}

// ---------------------------------------------------------------- prep: P = bf16(h * norm_src)
__global__ __launch_bounds__(256) void prep_hs_kernel(const float* __restrict__ h,
                               const float* __restrict__ norm_src,
                               unsigned short* __restrict__ hs) {
    int tid = blockIdx.x * blockDim.x + threadIdx.x;
    int v = tid >> 4;
    if (v >= N_NODES) return;
    int c8 = (tid & 15) << 3;
    float ns = norm_src[v];
    float4 a = *reinterpret_cast<const float4*>(h + (size_t)v * D + c8);
    float4 b = *reinterpret_cast<const float4*>(h + (size_t)v * D + c8 + 4);
    unsigned short o[8] = {f2bf(a.x * ns), f2bf(a.y * ns), f2bf(a.z * ns), f2bf(a.w * ns),
                           f2bf(b.x * ns), f2bf(b.y * ns), f2bf(b.z * ns), f2bf(b.w * ns)};
    *reinterpret_cast<u16x8*>(hs + (size_t)v * D + c8) = *reinterpret_cast<u16x8*>(o);
}

// ---------------------------------------------------------------- FUSED agg + MFMA GEMM + BN partials
// 64 nodes/block. Phase 1: gather-aggregate into swizzled LDS tile (bf16).
// Phase 2: 4 waves x (16 rows x 128 cols) MFMA from LDS. Epilogue: bias, BN
// partials, LDS C-transpose, coalesced bf16 store.
__global__ __launch_bounds__(256) void fused_kernel(const unsigned short* __restrict__ P,
        const int* __restrict__ rp, const int* __restrict__ col_idx,
        const float* __restrict__ norm_dst,
        const unsigned short* __restrict__ Wt, const float* __restrict__ bl,
        unsigned short* __restrict__ outB, float* __restrict__ pstats, int nrows) {
    __shared__ __align__(16) unsigned char smem[49152];  // sW 32KB | sAgg 16KB
    __shared__ float part[4 * 2 * 128];
    unsigned short* sW = reinterpret_cast<unsigned short*>(smem);
    unsigned char* sAgg = smem + 32768;
    int t = threadIdx.x;

    // stage W (pre-swizzled, linear copy)
#pragma unroll
    for (int i = 0; i < 8; ++i)
        reinterpret_cast<uint4*>(sW)[t + i * 256] = reinterpret_cast<const uint4*>(Wt)[t + i * 256];

    // ---- phase 1: aggregation into sAgg
    int rowbase = blockIdx.x * 64;
    int c8 = (t & 15) << 3;
#pragma unroll
    for (int ni = 0; ni < 4; ++ni) {
        int r = (t >> 4) + ni * 16;        // 0..63
        int v = rowbase + r;
        float acc[8] = {0.f, 0.f, 0.f, 0.f, 0.f, 0.f, 0.f, 0.f};
        if (v < nrows) {
            int e0 = rp[v], e1 = rp[v + 1];
            int e = e0;
            int e8 = e0 + ((e1 - e0) & ~7);
            for (; e < e8; e += 8) {
                int u[8];
#pragma unroll
                for (int q = 0; q < 8; ++q) u[q] = col_idx[e + q];
                u16x8 hv[8];
#pragma unroll
                for (int q = 0; q < 8; ++q)
                    hv[q] = *reinterpret_cast<const u16x8*>(P + (size_t)u[q] * D + c8);
#pragma unroll
                for (int j = 0; j < 8; ++j) {
                    float s01 = bf2f(hv[0][j]) + bf2f(hv[1][j]);
                    float s23 = bf2f(hv[2][j]) + bf2f(hv[3][j]);
                    float s45 = bf2f(hv[4][j]) + bf2f(hv[5][j]);
                    float s67 = bf2f(hv[6][j]) + bf2f(hv[7][j]);
                    acc[j] += (s01 + s23) + (s45 + s67);
                }
            }
            for (; e < e1; ++e) {
                int u = col_idx[e];
                u16x8 hv = *reinterpret_cast<const u16x8*>(P + (size_t)u * D + c8);
#pragma unroll
                for (int j = 0; j < 8; ++j) acc[j] += bf2f(hv[j]);
            }
            float nd = norm_dst[v];
#pragma unroll
            for (int j = 0; j < 8; ++j) acc[j] *= nd;
        }
        unsigned short o[8];
#pragma unroll
        for (int j = 0; j < 8; ++j) o[j] = f2bf(acc[j]);
        int boff = (r * 256 + c8 * 2) ^ ((r & 7) << 4);
        *reinterpret_cast<u16x8*>(sAgg + boff) = *reinterpret_cast<u16x8*>(o);
    }
    __syncthreads();

    // ---- phase 2: MFMA (wave w: rows w*16..w*16+15, cols 0..127)
    int wave = t >> 6;
    int lane = t & 63;
    int l15 = lane & 15;
    int lg = lane >> 4;

    f32x4 acc[8];
#pragma unroll
    for (int cf = 0; cf < 8; ++cf) acc[cf] = (f32x4){0.f, 0.f, 0.f, 0.f};

#pragma unroll
    for (int ks = 0; ks < 4; ++ks) {
        int aoff = ((wave * 16 + l15) * 256 + ks * 64 + lg * 16) ^ ((l15 & 7) << 4);
        bf16x8 a = *reinterpret_cast<const bf16x8*>(sAgg + aoff);
#pragma unroll
        for (int cf = 0; cf < 8; ++cf) {
            int col = cf * 16 + l15;
            int byteoff = (col * 256 + ks * 64 + lg * 16) ^ ((col & 7) << 4);
            bf16x8 bfrag = *reinterpret_cast<const bf16x8*>(
                reinterpret_cast<const char*>(sW) + byteoff);
            acc[cf] = __builtin_amdgcn_mfma_f32_16x16x32_bf16(a, bfrag, acc[cf], 0, 0, 0);
        }
    }
    __syncthreads();   // done reading sW/sAgg; reuse smem for C-transpose

    // ---- epilogue: bias + BN partials + LDS C-transpose (64 rows x 264B)
    char* cbuf = reinterpret_cast<char*>(smem);
#pragma unroll
    for (int cf = 0; cf < 8; ++cf) {
        int c = cf * 16 + l15;
        float bias = bl[c];
        float s = 0.f, sq = 0.f;
#pragma unroll
        for (int j = 0; j < 4; ++j) {
            int rl = wave * 16 + lg * 4 + j;
            float val = acc[cf][j] + bias;
            *reinterpret_cast<unsigned short*>(cbuf + rl * 264 + c * 2) = f2bf(val);
            if (rowbase + rl < nrows) { s += val; sq += val * val; }
        }
        s += __shfl_xor(s, 16);
        s += __shfl_xor(s, 32);
        sq += __shfl_xor(sq, 16);
        sq += __shfl_xor(sq, 32);
        if (lg == 0) {
            part[wave * 256 + c] = s;
            part[wave * 256 + 128 + c] = sq;
        }
    }
    __syncthreads();
    float tot = part[0 * 256 + (t >> 7) * 128 + (t & 127)]
              + part[1 * 256 + (t >> 7) * 128 + (t & 127)]
              + part[2 * 256 + (t >> 7) * 128 + (t & 127)]
              + part[3 * 256 + (t >> 7) * 128 + (t & 127)];
    pstats[(size_t)blockIdx.x * 256 + t] = tot;

    // coalesced store: 64 rows x 16 chunks of 16B
#pragma unroll
    for (int i = 0; i < 4; ++i) {
        int ch = t + i * 256;
        int r = ch >> 4, c16 = ch & 15;
        int grow = rowbase + r;
        if (grow < nrows) {
            u16x8 vv = *reinterpret_cast<u16x8*>(cbuf + r * 264 + c16 * 16);
            *reinterpret_cast<u16x8*>(outB + (size_t)grow * D + c16 * 8) = vv;
        }
    }
}

// ---------------------------------------------------------------- BN stat reduction + finalize
__global__ void reduce_pstats_kernel(const float* __restrict__ pstats, float* __restrict__ pstats2,
                                     int nblk) {
    int t = threadIdx.x;
    int bb = blockIdx.x;           // 16 blocks
    int chunk = (nblk + 15) / 16;
    int b0 = bb * chunk, b1 = min(b0 + chunk, nblk);
    float s = 0.f;
    for (int b = b0; b < b1; ++b) s += pstats[(size_t)b * 256 + t];
    pstats2[bb * 256 + t] = s;
}

__global__ void bn_finalize_kernel(const float* __restrict__ pstats2, const float* __restrict__ gamma,
                                   const float* __restrict__ beta, float* __restrict__ fin) {
    int c = threadIdx.x;   // 128
    float s = 0.f, sq = 0.f;
#pragma unroll
    for (int i = 0; i < 16; ++i) {
        s += pstats2[i * 256 + c];
        sq += pstats2[i * 256 + 128 + c];
    }
    float mu = s * (1.f / N_NODES);
    float var = sq * (1.f / N_NODES) - mu * mu;
    float sc = rsqrtf(var + BN_EPS) * gamma[c];
    fin[c] = sc;
    fin[D + c] = beta[c] - mu * sc;
}

// ---------------------------------------------------------------- BN apply (+relu,+residual), writes H and P
__global__ __launch_bounds__(256) void bn_apply_kernel(const unsigned short* __restrict__ G,
                                const unsigned short* __restrict__ Xres,
                                const float* __restrict__ fin, const float* __restrict__ norm_src,
                                unsigned short* __restrict__ Hout, unsigned short* __restrict__ hs,
                                int residual, int write_hs) {
    int tid = blockIdx.x * blockDim.x + threadIdx.x;
    int v = tid >> 4;
    if (v >= N_NODES) return;
    int c8 = (tid & 15) << 3;
    u16x8 gv = *reinterpret_cast<const u16x8*>(G + (size_t)v * D + c8);
    float4 sc0 = *reinterpret_cast<const float4*>(fin + c8);
    float4 sc1 = *reinterpret_cast<const float4*>(fin + c8 + 4);
    float4 sh0 = *reinterpret_cast<const float4*>(fin + D + c8);
    float4 sh1 = *reinterpret_cast<const float4*>(fin + D + c8 + 4);
    float sc[8] = {sc0.x, sc0.y, sc0.z, sc0.w, sc1.x, sc1.y, sc1.z, sc1.w};
    float sh[8] = {sh0.x, sh0.y, sh0.z, sh0.w, sh1.x, sh1.y, sh1.z, sh1.w};
    float o[8];
#pragma unroll
    for (int j = 0; j < 8; ++j) o[j] = fmaxf(fmaf(bf2f(gv[j]), sc[j], sh[j]), 0.f);
    if (residual) {
        u16x8 xv = *reinterpret_cast<const u16x8*>(Xres + (size_t)v * D + c8);
#pragma unroll
        for (int j = 0; j < 8; ++j) o[j] += bf2f(xv[j]);
    }
    unsigned short ob[8];
#pragma unroll
    for (int j = 0; j < 8; ++j) ob[j] = f2bf(o[j]);
    *reinterpret_cast<u16x8*>(Hout + (size_t)v * D + c8) = *reinterpret_cast<u16x8*>(ob);
    if (write_hs) {
        float ns = norm_src[v];
        unsigned short pb[8];
#pragma unroll
        for (int j = 0; j < 8; ++j) pb[j] = f2bf(o[j] * ns);
        *reinterpret_cast<u16x8*>(hs + (size_t)v * D + c8) = *reinterpret_cast<u16x8*>(pb);
    }
}

// ---------------------------------------------------------------- pooling (bf16 in) + head
__global__ __launch_bounds__(256) void pool_kernel(const unsigned short* __restrict__ h,
                            const int* __restrict__ gid,
                            float* __restrict__ pooled) {
    int base = blockIdx.x * 1024;
    int c8 = (threadIdx.x & 15) << 3;
    int sub = threadIdx.x >> 4;
    int r0 = base + sub * 64;
    if (r0 >= N_NODES) return;
    int r1 = min(r0 + 64, N_NODES);
    int gcur = gid[r0];
    float a[8] = {0.f, 0.f, 0.f, 0.f, 0.f, 0.f, 0.f, 0.f};
    for (int row = r0; row < r1; ++row) {
        int g = gid[row];
        u16x8 hv = *reinterpret_cast<const u16x8*>(h + (size_t)row * D + c8);
        if (g != gcur) {
#pragma unroll
            for (int j = 0; j < 8; ++j) { atomicAdd(&pooled[gcur * D + c8 + j], a[j]); a[j] = 0.f; }
            gcur = g;
        }
#pragma unroll
        for (int j = 0; j < 8; ++j) a[j] += bf2f(hv[j]);
    }
#pragma unroll
    for (int j = 0; j < 8; ++j) atomicAdd(&pooled[gcur * D + c8 + j], a[j]);
}

__global__ void head_kernel(const float* __restrict__ pooled, const float* __restrict__ Wp,
                            const float* __restrict__ bp, float* __restrict__ out) {
    int tid = blockIdx.x * blockDim.x + threadIdx.x;
    if (tid >= NGRAPH * NOUT) return;
    int g = tid / NOUT, o = tid % NOUT;
    float sum = bp[o];
    for (int k = 0; k < D; ++k) sum = fmaf(pooled[g * D + k], Wp[k * NOUT + o], sum);
    out[tid] = sum;
}

// ----------------------------------------------------------------
extern "C" void kernel_launch(void* const* d_in, const int* in_sizes, int n_in,
                              void* d_out, int out_size, void* d_ws, size_t ws_size,
                              hipStream_t stream) {
    const float* h     = (const float*)d_in[0];
    const float* W     = (const float*)d_in[1];
    const float* b     = (const float*)d_in[2];
    const float* gamma = (const float*)d_in[3];
    const float* beta  = (const float*)d_in[4];
    const float* Wp    = (const float*)d_in[5];
    const float* bp    = (const float*)d_in[6];
    const int*   src   = (const int*)d_in[7];
    const int*   dst   = (const int*)d_in[8];
    const int*   gid   = (const int*)d_in[9];
    float* out = (float*)d_out;

    char* ws = (char*)d_ws;
    size_t off = 0;
    auto alloc = [&](size_t bytes) { char* p = ws + off; off = (off + bytes + 511) & ~(size_t)511; return p; };
    unsigned short* Hb0 = (unsigned short*)alloc((size_t)N_NODES * D * 2);  // 25.6 MB
    unsigned short* Hb1 = (unsigned short*)alloc((size_t)N_NODES * D * 2);  // 25.6 MB
    unsigned short* Gb  = (unsigned short*)alloc((size_t)N_NODES * D * 2);  // gemm out
    unsigned short* P   = (unsigned short*)alloc((size_t)N_NODES * D * 2);  // h * norm_src
    unsigned short* Wt  = (unsigned short*)alloc((size_t)NLAYERS * D * D * 2);
    int*   partial  = (int*)alloc((size_t)DH_SL * DH_PAD * 4);              // 14.7 MB
    int*   row_ptr  = (int*)alloc((size_t)(N_NODES + 1) * 4);
    int*   col_idx  = (int*)alloc((size_t)N_EDGES * 4);
    float* norm_src = (float*)alloc((size_t)N_NODES * 4);
    float* norm_dst = (float*)alloc((size_t)N_NODES * 4);
    int*   ph1      = (int*)alloc((size_t)512 * SORT_B * 4);
    int*   blksum   = (int*)alloc(256 * 4);
    float* pstats   = (float*)alloc((size_t)FUSED_BLOCKS * 256 * 4);        // 1.6 MB
    float* pstats2  = (float*)alloc((size_t)16 * 256 * 4);
    float* fin      = (float*)alloc(2 * D * 4);
    float* pooled   = (float*)alloc((size_t)NGRAPH * D * 4);

    // sort scratch aliased into Gb (dead until first fused gemm)
    int2* kv1 = (int2*)Gb;   // 12.8 MB <= 25.6 MB

    // ---- deg_out histogram (range-partitioned LDS, no global atomics)
    deg_hist_kernel<<<DH_NR * DH_SL, 256, 0, stream>>>(src, partial);

    // ---- pass 1: 512-bin bucket by dst>>8
    hist1_kernel<<<SORT_B, 256, 0, stream>>>(dst, ph1);
    int n1 = 512 * SORT_B;
    scanA_kernel<<<(n1 + 2047) / 2048, 256, 0, stream>>>(ph1, blksum, n1);
    scanB_kernel<<<1, 256, 0, stream>>>(blksum, (n1 + 2047) / 2048);
    scanC_kernel<<<(n1 + 255) / 256, 256, 0, stream>>>(ph1, blksum, n1);
    place1_kernel<<<SORT_B, 256, 0, stream>>>(dst, src, ph1, kv1);

    // ---- pass 2: in-LDS counting sort per bin -> col_idx + row_ptr
    binsort_kernel<<<SORT_B, 256, 0, stream>>>(kv1, ph1, col_idx, row_ptr);

    // ---- norms + weight/input prep
    norms_kernel<<<(N_NODES + 255) / 256, 256, 0, stream>>>(partial, row_ptr, norm_src, norm_dst);
    wprep_kernel<<<(NLAYERS * D * D + 255) / 256, 256, 0, stream>>>(W, Wt);
    prep_hs_kernel<<<(N_NODES * 16 + 255) / 256, 256, 0, stream>>>(h, norm_src, P);

    // ---- layers (h ping-pong: l writes Hb[l&1], residual reads Hb[~l&1])
    for (int l = 0; l < NLAYERS; ++l) {
        unsigned short* Hout = (l & 1) ? Hb1 : Hb0;
        const unsigned short* Xres = (l & 1) ? Hb0 : Hb1;
        fused_kernel<<<FUSED_BLOCKS, 256, 0, stream>>>(P, row_ptr, col_idx, norm_dst,
                                                       Wt + (size_t)l * D * D,
                                                       b + (size_t)l * D, Gb, pstats, N_NODES);
        reduce_pstats_kernel<<<16, 256, 0, stream>>>(pstats, pstats2, FUSED_BLOCKS);
        bn_finalize_kernel<<<1, 128, 0, stream>>>(pstats2, gamma + (size_t)l * D,
                                                  beta + (size_t)l * D, fin);
        bn_apply_kernel<<<(N_NODES * 16 + 255) / 256, 256, 0, stream>>>(
            Gb, Xres, fin, norm_src, Hout, P, l > 0 ? 1 : 0, l < NLAYERS - 1 ? 1 : 0);
    }

    // ---- pooling + head (final h in Hb1)
    hipMemsetAsync(pooled, 0, (size_t)NGRAPH * D * 4, stream);
    pool_kernel<<<(N_NODES + 1023) / 1024, 256, 0, stream>>>(Hb1, gid, pooled);
    head_kernel<<<4, 256, 0, stream>>>(pooled, Wp, bp, out);
}

// Round 10
// 579.931 us; speedup vs baseline: 1.1643x; 1.1643x over previous
//
#include <hip/hip_runtime.h>

#define N_NODES 100000
#define N_EDGES 1600000
#define D 128
#define NLAYERS 4
#define NGRAPH 100
#define NOUT 10
#define BN_EPS 1e-5f

#define SORT_B 391     // pass-1 blocks: 391 * 4096 >= E; also 391 bins of dst>>8
#define BIN_CAP 6144   // max edges per high-bit bin

#define DH_NR 7        // deg-hist node ranges of 16384
#define DH_SL 32       // deg-hist edge slices
#define DH_RANGE 16384
#define DH_PAD (DH_NR * DH_RANGE)   // 114688

typedef __attribute__((ext_vector_type(8))) short bf16x8;
typedef __attribute__((ext_vector_type(8))) unsigned short u16x8;
typedef __attribute__((ext_vector_type(4))) float f32x4;

static __device__ __forceinline__ unsigned short f2bf(float f) {
    unsigned u = __builtin_bit_cast(unsigned, f);
    unsigned r = (u + 0x7fffu + ((u >> 16) & 1u)) >> 16;
    return (unsigned short)r;
}
static __device__ __forceinline__ float bf2f(unsigned short b) {
    unsigned u = ((unsigned)b) << 16;
    return __builtin_bit_cast(float, u);
}

// ---------------------------------------------------------------- deg_out histogram, zero global atomics
__global__ __launch_bounds__(256) void deg_hist_kernel(const int* __restrict__ src,
                                                       int* __restrict__ partial) {
    __shared__ int hist[DH_RANGE];   // 64 KB
    int t = threadIdx.x;
    int r = blockIdx.x / DH_SL;
    int s = blockIdx.x % DH_SL;
#pragma unroll
    for (int i = 0; i < 16; ++i)
        reinterpret_cast<int4*>(hist)[t + i * 256] = make_int4(0, 0, 0, 0);
    __syncthreads();
    int lo = r * DH_RANGE, hi = lo + DH_RANGE;
    int e0 = s * (N_EDGES / DH_SL);
    for (int i = t; i < (N_EDGES / DH_SL) / 4; i += 256) {
        int4 v = *reinterpret_cast<const int4*>(src + e0 + i * 4);
        if (v.x >= lo && v.x < hi) atomicAdd(&hist[v.x - lo], 1);
        if (v.y >= lo && v.y < hi) atomicAdd(&hist[v.y - lo], 1);
        if (v.z >= lo && v.z < hi) atomicAdd(&hist[v.z - lo], 1);
        if (v.w >= lo && v.w < hi) atomicAdd(&hist[v.w - lo], 1);
    }
    __syncthreads();
    int4* dst4 = reinterpret_cast<int4*>(partial + (size_t)s * DH_PAD + lo);
#pragma unroll
    for (int i = 0; i < 16; ++i)
        dst4[t + i * 256] = reinterpret_cast<int4*>(hist)[t + i * 256];
}

// ---------------------------------------------------------------- pass 1 hist (512 bins by dst>>8)
__global__ __launch_bounds__(256) void hist1_kernel(const int* __restrict__ dst,
                                                    int* __restrict__ ph) {
    __shared__ int h[512];
    int t = threadIdx.x;
    h[t] = 0; h[t + 256] = 0;
    __syncthreads();
    int base = blockIdx.x * 4096;
#pragma unroll
    for (int i = 0; i < 4; ++i) {
        int e = base + (t + i * 256) * 4;
        if (e + 3 < N_EDGES) {
            int4 v = *reinterpret_cast<const int4*>(dst + e);
            atomicAdd(&h[v.x >> 8], 1);
            atomicAdd(&h[v.y >> 8], 1);
            atomicAdd(&h[v.z >> 8], 1);
            atomicAdd(&h[v.w >> 8], 1);
        } else {
            for (int q = 0; q < 4; ++q)
                if (e + q < N_EDGES) atomicAdd(&h[dst[e + q] >> 8], 1);
        }
    }
    __syncthreads();
    ph[t * SORT_B + blockIdx.x] = h[t];
    ph[(t + 256) * SORT_B + blockIdx.x] = h[t + 256];
}

__global__ __launch_bounds__(256) void place1_kernel(const int* __restrict__ dst,
        const int* __restrict__ src, const int* __restrict__ ph,
        int2* __restrict__ kv1) {
    __shared__ int cur[512];
    int t = threadIdx.x;
    cur[t] = ph[t * SORT_B + blockIdx.x];
    cur[t + 256] = ph[(t + 256) * SORT_B + blockIdx.x];
    __syncthreads();
    int base = blockIdx.x * 4096;
#pragma unroll
    for (int i = 0; i < 16; ++i) {
        int e = base + i * 256 + t;
        if (e < N_EDGES) {
            int k = dst[e];
            int pos = atomicAdd(&cur[k >> 8], 1);
            kv1[pos] = make_int2(k, src[e]);
        }
    }
}

// ---------------------------------------------------------------- pass 2: in-LDS counting sort per bin
__global__ __launch_bounds__(256) void binsort_kernel(const int2* __restrict__ kv1,
        const int* __restrict__ ph, int* __restrict__ col, int* __restrict__ rp) {
    __shared__ int vsh[BIN_CAP];
    __shared__ int osh[BIN_CAP];
    __shared__ unsigned char ksh[BIN_CAP];
    __shared__ int hist[256];
    __shared__ int sc[256];
    __shared__ int cur[256];
    int t = threadIdx.x;
    int b = blockIdx.x;
    int start = ph[b * SORT_B];
    int end = (b == SORT_B - 1) ? N_EDGES : ph[(b + 1) * SORT_B];
    int n = end - start;
    if (n > BIN_CAP) n = BIN_CAP;
    hist[t] = 0;
    __syncthreads();
    for (int i = t; i < n; i += 256) {
        int2 kv = kv1[start + i];
        int d = kv.x & 255;
        ksh[i] = (unsigned char)d;
        vsh[i] = kv.y;
        atomicAdd(&hist[d], 1);
    }
    __syncthreads();
    int hv = hist[t];
    sc[t] = hv;
    __syncthreads();
    for (int off = 1; off < 256; off <<= 1) {
        int x = 0;
        if (t >= off) x = sc[t - off];
        __syncthreads();
        sc[t] += x;
        __syncthreads();
    }
    int pos = sc[t] - hv;
    cur[t] = pos;
    int v = b * 256 + t;
    if (v < N_NODES) rp[v] = start + pos;
    if (b == SORT_B - 1 && t == 0) rp[N_NODES] = N_EDGES;
    __syncthreads();
    for (int i = t; i < n; i += 256) {
        int d = ksh[i];
        int p = atomicAdd(&cur[d], 1);
        osh[p] = vsh[i];
    }
    __syncthreads();
    for (int i = t; i < n; i += 256) col[start + i] = osh[i];
}

// ---------------------------------------------------------------- generalized scan (exclusive)
__global__ void scanA_kernel(int* __restrict__ data, int* __restrict__ blksum, int n) {
    __shared__ int s[256];
    int t = threadIdx.x;
    int base = blockIdx.x * 2048 + t * 8;
    int v[8]; int sum = 0;
#pragma unroll
    for (int j = 0; j < 8; ++j) { v[j] = (base + j < n) ? data[base + j] : 0; sum += v[j]; }
    s[t] = sum;
    __syncthreads();
    for (int off = 1; off < 256; off <<= 1) {
        int x = 0;
        if (t >= off) x = s[t - off];
        __syncthreads();
        s[t] += x;
        __syncthreads();
    }
    int run = s[t] - sum;
#pragma unroll
    for (int j = 0; j < 8; ++j) { if (base + j < n) data[base + j] = run; run += v[j]; }
    if (t == 255) blksum[blockIdx.x] = s[255];
}

__global__ void scanB_kernel(int* __restrict__ blksum, int nb) {
    __shared__ int s[256];
    int t = threadIdx.x;
    int v = (t < nb) ? blksum[t] : 0;
    s[t] = v;
    __syncthreads();
    for (int off = 1; off < 256; off <<= 1) {
        int x = 0;
        if (t >= off) x = s[t - off];
        __syncthreads();
        s[t] += x;
        __syncthreads();
    }
    if (t < nb) blksum[t] = s[t] - v;
}

__global__ void scanC_kernel(int* __restrict__ data, const int* __restrict__ blksum, int n) {
    int i = blockIdx.x * blockDim.x + threadIdx.x;
    if (i < n) data[i] += blksum[i >> 11];
}

// ---------------------------------------------------------------- norms
__global__ void norms_kernel(const int* __restrict__ partial, const int* __restrict__ rp,
                             float* __restrict__ norm_src, float* __restrict__ norm_dst) {
    int v = blockIdx.x * blockDim.x + threadIdx.x;
    if (v < N_NODES) {
        int d = 0;
#pragma unroll
        for (int s = 0; s < DH_SL; ++s) d += partial[(size_t)s * DH_PAD + v];
        norm_src[v] = rsqrtf((float)max(d, 1));
        norm_dst[v] = rsqrtf((float)max(rp[v + 1] - rp[v], 1));
    }
}

// ---------------------------------------------------------------- weight prep (bf16, B^T, XOR-swizzled)
__global__ void wprep_kernel(const float* __restrict__ W, unsigned short* __restrict__ Wt) {
    int i = blockIdx.x * blockDim.x + threadIdx.x;
    if (i >= NLAYERS * D * D) return;
    int l = i >> 14;
    int r = i & (D * D - 1);
    int col = r >> 7;
    int k = r & 127;
    float v = W[(size_t)l * D * D + k * D + col];
    int byteoff = col * 256 + k * 2;
    int swz = byteoff ^ ((col & 7) << 4);
    Wt[(size_t)l * D * D + (swz >> 1)] = f2bf(v);
}

// ---------------------------------------------------------------- prep: P = bf16(h * norm_src)
__global__ __launch_bounds__(256) void prep_hs_kernel(const float* __restrict__ h,
                               const float* __restrict__ norm_src,
                               unsigned short* __restrict__ hs) {
    int tid = blockIdx.x * blockDim.x + threadIdx.x;
    int v = tid >> 4;
    if (v >= N_NODES) return;
    int c8 = (tid & 15) << 3;
    float ns = norm_src[v];
    float4 a = *reinterpret_cast<const float4*>(h + (size_t)v * D + c8);
    float4 b = *reinterpret_cast<const float4*>(h + (size_t)v * D + c8 + 4);
    unsigned short o[8] = {f2bf(a.x * ns), f2bf(a.y * ns), f2bf(a.z * ns), f2bf(a.w * ns),
                           f2bf(b.x * ns), f2bf(b.y * ns), f2bf(b.z * ns), f2bf(b.w * ns)};
    *reinterpret_cast<u16x8*>(hs + (size_t)v * D + c8) = *reinterpret_cast<u16x8*>(o);
}

// ---------------------------------------------------------------- aggregation (R6 form: pre-scaled P, 8x MLP unroll)
__global__ __launch_bounds__(256) void agg_kernel(const unsigned short* __restrict__ hs,
                           const int* __restrict__ rp,
                           const int* __restrict__ col_idx, const float* __restrict__ norm_dst,
                           unsigned short* __restrict__ aggb) {
    int tid = blockIdx.x * blockDim.x + threadIdx.x;
    int v = tid >> 4;
    if (v >= N_NODES) return;
    int c8 = (tid & 15) << 3;
    int e0 = rp[v], e1 = rp[v + 1];
    float acc[8] = {0.f, 0.f, 0.f, 0.f, 0.f, 0.f, 0.f, 0.f};
    int e = e0;
    int e8 = e0 + ((e1 - e0) & ~7);
    for (; e < e8; e += 8) {
        int u[8];
#pragma unroll
        for (int q = 0; q < 8; ++q) u[q] = col_idx[e + q];
        u16x8 hv[8];
#pragma unroll
        for (int q = 0; q < 8; ++q)
            hv[q] = *reinterpret_cast<const u16x8*>(hs + (size_t)u[q] * D + c8);
#pragma unroll
        for (int j = 0; j < 8; ++j) {
            float s01 = bf2f(hv[0][j]) + bf2f(hv[1][j]);
            float s23 = bf2f(hv[2][j]) + bf2f(hv[3][j]);
            float s45 = bf2f(hv[4][j]) + bf2f(hv[5][j]);
            float s67 = bf2f(hv[6][j]) + bf2f(hv[7][j]);
            acc[j] += (s01 + s23) + (s45 + s67);
        }
    }
    for (; e < e1; ++e) {
        int u = col_idx[e];
        u16x8 hv = *reinterpret_cast<const u16x8*>(hs + (size_t)u * D + c8);
#pragma unroll
        for (int j = 0; j < 8; ++j) acc[j] += bf2f(hv[j]);
    }
    float nd = norm_dst[v];
    unsigned short o[8];
#pragma unroll
    for (int j = 0; j < 8; ++j) o[j] = f2bf(acc[j] * nd);
    *reinterpret_cast<u16x8*>(aggb + (size_t)v * D + c8) = *reinterpret_cast<u16x8*>(o);
}

// ---------------------------------------------------------------- MFMA GEMM (bf16 out) + per-block BN partials
__global__ __launch_bounds__(256) void gemm_mfma_kernel(const unsigned short* __restrict__ A,
        const unsigned short* __restrict__ Wt, const float* __restrict__ bl,
        unsigned short* __restrict__ outB, float* __restrict__ pstats, int nrows) {
    __shared__ __align__(16) unsigned char smem[33792];  // Wt stage (32KB) then C-transpose
    __shared__ float part[4 * 2 * 128];
    unsigned short* sW = reinterpret_cast<unsigned short*>(smem);
    int t = threadIdx.x;
#pragma unroll
    for (int i = 0; i < 8; ++i) {
        int idx = t + i * 256;
        reinterpret_cast<uint4*>(sW)[idx] = reinterpret_cast<const uint4*>(Wt)[idx];
    }
    __syncthreads();

    int wave = t >> 6;
    int lane = t & 63;
    int l15 = lane & 15;
    int lg = lane >> 4;
    int rowbase = blockIdx.x * 128 + wave * 32;

    f32x4 acc[2][8];
#pragma unroll
    for (int rf = 0; rf < 2; ++rf)
#pragma unroll
        for (int cf = 0; cf < 8; ++cf) acc[rf][cf] = (f32x4){0.f, 0.f, 0.f, 0.f};

    int rA[2];
#pragma unroll
    for (int rf = 0; rf < 2; ++rf) {
        int r = rowbase + rf * 16 + l15;
        rA[rf] = (r >= nrows) ? nrows - 1 : r;
    }

#pragma unroll
    for (int ks = 0; ks < 4; ++ks) {
        bf16x8 a[2];
#pragma unroll
        for (int rf = 0; rf < 2; ++rf)
            a[rf] = *reinterpret_cast<const bf16x8*>(A + (size_t)rA[rf] * D + ks * 32 + lg * 8);
#pragma unroll
        for (int cf = 0; cf < 8; ++cf) {
            int col = cf * 16 + l15;
            int byteoff = (col * 256 + ks * 64 + lg * 16) ^ ((col & 7) << 4);
            bf16x8 bfrag = *reinterpret_cast<const bf16x8*>(
                reinterpret_cast<const char*>(sW) + byteoff);
            acc[0][cf] = __builtin_amdgcn_mfma_f32_16x16x32_bf16(a[0], bfrag, acc[0][cf], 0, 0, 0);
            acc[1][cf] = __builtin_amdgcn_mfma_f32_16x16x32_bf16(a[1], bfrag, acc[1][cf], 0, 0, 0);
        }
    }

    __syncthreads();   // all waves done reading sW; reuse smem for C-transpose
    char* wbase = reinterpret_cast<char*>(smem) + wave * 8448;   // 32 rows x 264B

#pragma unroll
    for (int cf = 0; cf < 8; ++cf) {
        int c = cf * 16 + l15;
        float bias = bl[c];
        float s = 0.f, sq = 0.f;
#pragma unroll
        for (int rf = 0; rf < 2; ++rf) {
#pragma unroll
            for (int j = 0; j < 4; ++j) {
                int rl = rf * 16 + lg * 4 + j;
                float val = acc[rf][cf][j] + bias;
                *reinterpret_cast<unsigned short*>(wbase + rl * 264 + c * 2) = f2bf(val);
                if (rowbase + rl < nrows) { s += val; sq += val * val; }
            }
        }
        s += __shfl_xor(s, 16);
        s += __shfl_xor(s, 32);
        sq += __shfl_xor(sq, 16);
        sq += __shfl_xor(sq, 32);
        if (lg == 0) {
            part[wave * 256 + c] = s;
            part[wave * 256 + 128 + c] = sq;
        }
    }
    __syncthreads();
    float tot = part[0 * 256 + (t >> 7) * 128 + (t & 127)]
              + part[1 * 256 + (t >> 7) * 128 + (t & 127)]
              + part[2 * 256 + (t >> 7) * 128 + (t & 127)]
              + part[3 * 256 + (t >> 7) * 128 + (t & 127)];
    pstats[(size_t)blockIdx.x * 256 + t] = tot;

    int rl = lane >> 1;
    int colbase = (lane & 1) * 64;
    int grow = rowbase + rl;
    if (grow < nrows) {
#pragma unroll
        for (int k = 0; k < 8; ++k) {
            u16x8 vv = *reinterpret_cast<u16x8*>(wbase + rl * 264 + (colbase + k * 8) * 2);
            *reinterpret_cast<u16x8*>(outB + (size_t)grow * D + colbase + k * 8) = vv;
        }
    }
}

// ---------------------------------------------------------------- BN stat reduction + finalize
__global__ void reduce_pstats_kernel(const float* __restrict__ pstats, float* __restrict__ pstats2,
                                     int nblk) {
    int t = threadIdx.x;
    int bb = blockIdx.x;           // 16 blocks
    int chunk = (nblk + 15) / 16;
    int b0 = bb * chunk, b1 = min(b0 + chunk, nblk);
    float s = 0.f;
    for (int b = b0; b < b1; ++b) s += pstats[(size_t)b * 256 + t];
    pstats2[bb * 256 + t] = s;
}

__global__ void bn_finalize_kernel(const float* __restrict__ pstats2, const float* __restrict__ gamma,
                                   const float* __restrict__ beta, float* __restrict__ fin) {
    int c = threadIdx.x;   // 128
    float s = 0.f, sq = 0.f;
#pragma unroll
    for (int i = 0; i < 16; ++i) {
        s += pstats2[i * 256 + c];
        sq += pstats2[i * 256 + 128 + c];
    }
    float mu = s * (1.f / N_NODES);
    float var = sq * (1.f / N_NODES) - mu * mu;
    float sc = rsqrtf(var + BN_EPS) * gamma[c];
    fin[c] = sc;
    fin[D + c] = beta[c] - mu * sc;
}

// ---------------------------------------------------------------- BN apply (+relu,+residual), writes H and P
__global__ __launch_bounds__(256) void bn_apply_kernel(const unsigned short* __restrict__ G,
                                const unsigned short* __restrict__ Xres,
                                const float* __restrict__ fin, const float* __restrict__ norm_src,
                                unsigned short* __restrict__ Hout, unsigned short* __restrict__ hs,
                                int residual, int write_hs) {
    int tid = blockIdx.x * blockDim.x + threadIdx.x;
    int v = tid >> 4;
    if (v >= N_NODES) return;
    int c8 = (tid & 15) << 3;
    u16x8 gv = *reinterpret_cast<const u16x8*>(G + (size_t)v * D + c8);
    float4 sc0 = *reinterpret_cast<const float4*>(fin + c8);
    float4 sc1 = *reinterpret_cast<const float4*>(fin + c8 + 4);
    float4 sh0 = *reinterpret_cast<const float4*>(fin + D + c8);
    float4 sh1 = *reinterpret_cast<const float4*>(fin + D + c8 + 4);
    float sc[8] = {sc0.x, sc0.y, sc0.z, sc0.w, sc1.x, sc1.y, sc1.z, sc1.w};
    float sh[8] = {sh0.x, sh0.y, sh0.z, sh0.w, sh1.x, sh1.y, sh1.z, sh1.w};
    float o[8];
#pragma unroll
    for (int j = 0; j < 8; ++j) o[j] = fmaxf(fmaf(bf2f(gv[j]), sc[j], sh[j]), 0.f);
    if (residual) {
        u16x8 xv = *reinterpret_cast<const u16x8*>(Xres + (size_t)v * D + c8);
#pragma unroll
        for (int j = 0; j < 8; ++j) o[j] += bf2f(xv[j]);
    }
    unsigned short ob[8];
#pragma unroll
    for (int j = 0; j < 8; ++j) ob[j] = f2bf(o[j]);
    *reinterpret_cast<u16x8*>(Hout + (size_t)v * D + c8) = *reinterpret_cast<u16x8*>(ob);
    if (write_hs) {
        float ns = norm_src[v];
        unsigned short pb[8];
#pragma unroll
        for (int j = 0; j < 8; ++j) pb[j] = f2bf(o[j] * ns);
        *reinterpret_cast<u16x8*>(hs + (size_t)v * D + c8) = *reinterpret_cast<u16x8*>(pb);
    }
}

// ---------------------------------------------------------------- pooling (bf16 in) + head
__global__ __launch_bounds__(256) void pool_kernel(const unsigned short* __restrict__ h,
                            const int* __restrict__ gid,
                            float* __restrict__ pooled) {
    int base = blockIdx.x * 1024;
    int c8 = (threadIdx.x & 15) << 3;
    int sub = threadIdx.x >> 4;
    int r0 = base + sub * 64;
    if (r0 >= N_NODES) return;
    int r1 = min(r0 + 64, N_NODES);
    int gcur = gid[r0];
    float a[8] = {0.f, 0.f, 0.f, 0.f, 0.f, 0.f, 0.f, 0.f};
    for (int row = r0; row < r1; ++row) {
        int g = gid[row];
        u16x8 hv = *reinterpret_cast<const u16x8*>(h + (size_t)row * D + c8);
        if (g != gcur) {
#pragma unroll
            for (int j = 0; j < 8; ++j) { atomicAdd(&pooled[gcur * D + c8 + j], a[j]); a[j] = 0.f; }
            gcur = g;
        }
#pragma unroll
        for (int j = 0; j < 8; ++j) a[j] += bf2f(hv[j]);
    }
#pragma unroll
    for (int j = 0; j < 8; ++j) atomicAdd(&pooled[gcur * D + c8 + j], a[j]);
}

__global__ void head_kernel(const float* __restrict__ pooled, const float* __restrict__ Wp,
                            const float* __restrict__ bp, float* __restrict__ out) {
    int tid = blockIdx.x * blockDim.x + threadIdx.x;
    if (tid >= NGRAPH * NOUT) return;
    int g = tid / NOUT, o = tid % NOUT;
    float sum = bp[o];
    for (int k = 0; k < D; ++k) sum = fmaf(pooled[g * D + k], Wp[k * NOUT + o], sum);
    out[tid] = sum;
}

// ----------------------------------------------------------------
extern "C" void kernel_launch(void* const* d_in, const int* in_sizes, int n_in,
                              void* d_out, int out_size, void* d_ws, size_t ws_size,
                              hipStream_t stream) {
    const float* h     = (const float*)d_in[0];
    const float* W     = (const float*)d_in[1];
    const float* b     = (const float*)d_in[2];
    const float* gamma = (const float*)d_in[3];
    const float* beta  = (const float*)d_in[4];
    const float* Wp    = (const float*)d_in[5];
    const float* bp    = (const float*)d_in[6];
    const int*   src   = (const int*)d_in[7];
    const int*   dst   = (const int*)d_in[8];
    const int*   gid   = (const int*)d_in[9];
    float* out = (float*)d_out;

    char* ws = (char*)d_ws;
    size_t off = 0;
    auto alloc = [&](size_t bytes) { char* p = ws + off; off = (off + bytes + 511) & ~(size_t)511; return p; };
    unsigned short* Hb0 = (unsigned short*)alloc((size_t)N_NODES * D * 2);  // 25.6 MB
    unsigned short* Hb1 = (unsigned short*)alloc((size_t)N_NODES * D * 2);  // 25.6 MB
    unsigned short* Gb  = (unsigned short*)alloc((size_t)N_NODES * D * 2);  // gemm out
    unsigned short* P   = (unsigned short*)alloc((size_t)N_NODES * D * 2);  // h * norm_src
    unsigned short* Q   = (unsigned short*)alloc((size_t)N_NODES * D * 2);  // agg out
    unsigned short* Wt  = (unsigned short*)alloc((size_t)NLAYERS * D * D * 2);
    int*   partial  = (int*)alloc((size_t)DH_SL * DH_PAD * 4);              // 14.7 MB
    int*   row_ptr  = (int*)alloc((size_t)(N_NODES + 1) * 4);
    int*   col_idx  = (int*)alloc((size_t)N_EDGES * 4);
    float* norm_src = (float*)alloc((size_t)N_NODES * 4);
    float* norm_dst = (float*)alloc((size_t)N_NODES * 4);
    int*   ph1      = (int*)alloc((size_t)512 * SORT_B * 4);
    int*   blksum   = (int*)alloc(256 * 4);
    float* pstats   = (float*)alloc((size_t)782 * 256 * 4);
    float* pstats2  = (float*)alloc((size_t)16 * 256 * 4);
    float* fin      = (float*)alloc(2 * D * 4);
    float* pooled   = (float*)alloc((size_t)NGRAPH * D * 4);

    // sort scratch aliased into Gb (dead until first gemm)
    int2* kv1 = (int2*)Gb;   // 12.8 MB <= 25.6 MB

    // ---- deg_out histogram (range-partitioned LDS, no global atomics)
    deg_hist_kernel<<<DH_NR * DH_SL, 256, 0, stream>>>(src, partial);

    // ---- pass 1: 512-bin bucket by dst>>8
    hist1_kernel<<<SORT_B, 256, 0, stream>>>(dst, ph1);
    int n1 = 512 * SORT_B;
    scanA_kernel<<<(n1 + 2047) / 2048, 256, 0, stream>>>(ph1, blksum, n1);
    scanB_kernel<<<1, 256, 0, stream>>>(blksum, (n1 + 2047) / 2048);
    scanC_kernel<<<(n1 + 255) / 256, 256, 0, stream>>>(ph1, blksum, n1);
    place1_kernel<<<SORT_B, 256, 0, stream>>>(dst, src, ph1, kv1);

    // ---- pass 2: in-LDS counting sort per bin -> col_idx + row_ptr
    binsort_kernel<<<SORT_B, 256, 0, stream>>>(kv1, ph1, col_idx, row_ptr);

    // ---- norms + weight/input prep
    norms_kernel<<<(N_NODES + 255) / 256, 256, 0, stream>>>(partial, row_ptr, norm_src, norm_dst);
    wprep_kernel<<<(NLAYERS * D * D + 255) / 256, 256, 0, stream>>>(W, Wt);
    prep_hs_kernel<<<(N_NODES * 16 + 255) / 256, 256, 0, stream>>>(h, norm_src, P);

    // ---- layers (h ping-pong: l writes Hb[l&1], residual reads Hb[~l&1])
    int gemm_blocks = (N_NODES + 127) / 128;   // 782
    for (int l = 0; l < NLAYERS; ++l) {
        unsigned short* Hout = (l & 1) ? Hb1 : Hb0;
        const unsigned short* Xres = (l & 1) ? Hb0 : Hb1;
        agg_kernel<<<(N_NODES * 16 + 255) / 256, 256, 0, stream>>>(P, row_ptr, col_idx,
                                                                   norm_dst, Q);
        gemm_mfma_kernel<<<gemm_blocks, 256, 0, stream>>>(Q, Wt + (size_t)l * D * D,
                                                          b + (size_t)l * D, Gb, pstats, N_NODES);
        reduce_pstats_kernel<<<16, 256, 0, stream>>>(pstats, pstats2, gemm_blocks);
        bn_finalize_kernel<<<1, 128, 0, stream>>>(pstats2, gamma + (size_t)l * D,
                                                  beta + (size_t)l * D, fin);
        bn_apply_kernel<<<(N_NODES * 16 + 255) / 256, 256, 0, stream>>>(
            Gb, Xres, fin, norm_src, Hout, P, l > 0 ? 1 : 0, l < NLAYERS - 1 ? 1 : 0);
    }

    // ---- pooling + head (final h in Hb1)
    hipMemsetAsync(pooled, 0, (size_t)NGRAPH * D * 4, stream);
    pool_kernel<<<(N_NODES + 1023) / 1024, 256, 0, stream>>>(Hb1, gid, pooled);
    head_kernel<<<4, 256, 0, stream>>>(pooled, Wp, bp, out);
}

// Round 11
// 566.126 us; speedup vs baseline: 1.1926x; 1.0244x over previous
//
#include <hip/hip_runtime.h>

#define N_NODES 100000
#define N_EDGES 1600000
#define D 128
#define NLAYERS 4
#define NGRAPH 100
#define NOUT 10
#define BN_EPS 1e-5f

#define SORT_B 391     // pass-1 blocks: 391 * 4096 >= E; also 391 bins of dst>>8
#define BIN_CAP 6144   // max edges per high-bit bin

#define DH_NR 7        // deg-hist node ranges of 16384
#define DH_SL 32       // deg-hist edge slices
#define DH_RANGE 16384
#define DH_PAD (DH_NR * DH_RANGE)   // 114688

typedef __attribute__((ext_vector_type(8))) short bf16x8;
typedef __attribute__((ext_vector_type(8))) unsigned short u16x8;
typedef __attribute__((ext_vector_type(4))) float f32x4;

static __device__ __forceinline__ unsigned short f2bf(float f) {
    unsigned u = __builtin_bit_cast(unsigned, f);
    unsigned r = (u + 0x7fffu + ((u >> 16) & 1u)) >> 16;
    return (unsigned short)r;
}
static __device__ __forceinline__ float bf2f(unsigned short b) {
    unsigned u = ((unsigned)b) << 16;
    return __builtin_bit_cast(float, u);
}

// ---------------------------------------------------------------- deg_out histogram -> ushort partials
__global__ __launch_bounds__(256) void deg_hist_kernel(const int* __restrict__ src,
                                                       unsigned short* __restrict__ partial) {
    __shared__ int hist[DH_RANGE];   // 64 KB
    int t = threadIdx.x;
    int r = blockIdx.x / DH_SL;
    int s = blockIdx.x % DH_SL;
#pragma unroll
    for (int i = 0; i < 16; ++i)
        reinterpret_cast<int4*>(hist)[t + i * 256] = make_int4(0, 0, 0, 0);
    __syncthreads();
    int lo = r * DH_RANGE, hi = lo + DH_RANGE;
    int e0 = s * (N_EDGES / DH_SL);
    for (int i = t; i < (N_EDGES / DH_SL) / 4; i += 256) {
        int4 v = *reinterpret_cast<const int4*>(src + e0 + i * 4);
        if (v.x >= lo && v.x < hi) atomicAdd(&hist[v.x - lo], 1);
        if (v.y >= lo && v.y < hi) atomicAdd(&hist[v.y - lo], 1);
        if (v.z >= lo && v.z < hi) atomicAdd(&hist[v.z - lo], 1);
        if (v.w >= lo && v.w < hi) atomicAdd(&hist[v.w - lo], 1);
    }
    __syncthreads();
    // write as ushort: 8 counters per 16B chunk, 8 chunks per thread
    unsigned short* dstp = partial + (size_t)s * DH_PAD + lo;
#pragma unroll
    for (int i = 0; i < 8; ++i) {
        int base = (t + i * 256) * 8;
        unsigned short o[8];
#pragma unroll
        for (int j = 0; j < 8; ++j) o[j] = (unsigned short)hist[base + j];
        *reinterpret_cast<u16x8*>(dstp + base) = *reinterpret_cast<u16x8*>(o);
    }
}

// ---------------------------------------------------------------- pass 1 hist (512 bins by dst>>8)
__global__ __launch_bounds__(256) void hist1_kernel(const int* __restrict__ dst,
                                                    int* __restrict__ ph) {
    __shared__ int h[512];
    int t = threadIdx.x;
    h[t] = 0; h[t + 256] = 0;
    __syncthreads();
    int base = blockIdx.x * 4096;
#pragma unroll
    for (int i = 0; i < 4; ++i) {
        int e = base + (t + i * 256) * 4;
        if (e + 3 < N_EDGES) {
            int4 v = *reinterpret_cast<const int4*>(dst + e);
            atomicAdd(&h[v.x >> 8], 1);
            atomicAdd(&h[v.y >> 8], 1);
            atomicAdd(&h[v.z >> 8], 1);
            atomicAdd(&h[v.w >> 8], 1);
        } else {
            for (int q = 0; q < 4; ++q)
                if (e + q < N_EDGES) atomicAdd(&h[dst[e + q] >> 8], 1);
        }
    }
    __syncthreads();
    ph[t * SORT_B + blockIdx.x] = h[t];
    ph[(t + 256) * SORT_B + blockIdx.x] = h[t + 256];
}

__global__ __launch_bounds__(256) void place1_kernel(const int* __restrict__ dst,
        const int* __restrict__ src, const int* __restrict__ ph,
        int2* __restrict__ kv1) {
    __shared__ int cur[512];
    int t = threadIdx.x;
    cur[t] = ph[t * SORT_B + blockIdx.x];
    cur[t + 256] = ph[(t + 256) * SORT_B + blockIdx.x];
    __syncthreads();
    int base = blockIdx.x * 4096;
#pragma unroll
    for (int i = 0; i < 16; ++i) {
        int e = base + i * 256 + t;
        if (e < N_EDGES) {
            int k = dst[e];
            int pos = atomicAdd(&cur[k >> 8], 1);
            kv1[pos] = make_int2(k, src[e]);
        }
    }
}

// ---------------------------------------------------------------- pass 2: in-LDS counting sort per bin
__global__ __launch_bounds__(256) void binsort_kernel(const int2* __restrict__ kv1,
        const int* __restrict__ ph, int* __restrict__ col, int* __restrict__ rp) {
    __shared__ int vsh[BIN_CAP];
    __shared__ int osh[BIN_CAP];
    __shared__ unsigned char ksh[BIN_CAP];
    __shared__ int hist[256];
    __shared__ int sc[256];
    __shared__ int cur[256];
    int t = threadIdx.x;
    int b = blockIdx.x;
    int start = ph[b * SORT_B];
    int end = (b == SORT_B - 1) ? N_EDGES : ph[(b + 1) * SORT_B];
    int n = end - start;
    if (n > BIN_CAP) n = BIN_CAP;
    hist[t] = 0;
    __syncthreads();
    for (int i = t; i < n; i += 256) {
        int2 kv = kv1[start + i];
        int d = kv.x & 255;
        ksh[i] = (unsigned char)d;
        vsh[i] = kv.y;
        atomicAdd(&hist[d], 1);
    }
    __syncthreads();
    int hv = hist[t];
    sc[t] = hv;
    __syncthreads();
    for (int off = 1; off < 256; off <<= 1) {
        int x = 0;
        if (t >= off) x = sc[t - off];
        __syncthreads();
        sc[t] += x;
        __syncthreads();
    }
    int pos = sc[t] - hv;
    cur[t] = pos;
    int v = b * 256 + t;
    if (v < N_NODES) rp[v] = start + pos;
    if (b == SORT_B - 1 && t == 0) rp[N_NODES] = N_EDGES;
    __syncthreads();
    for (int i = t; i < n; i += 256) {
        int d = ksh[i];
        int p = atomicAdd(&cur[d], 1);
        osh[p] = vsh[i];
    }
    __syncthreads();
    for (int i = t; i < n; i += 256) col[start + i] = osh[i];
}

// ---------------------------------------------------------------- generalized scan (exclusive)
__global__ void scanA_kernel(int* __restrict__ data, int* __restrict__ blksum, int n) {
    __shared__ int s[256];
    int t = threadIdx.x;
    int base = blockIdx.x * 2048 + t * 8;
    int v[8]; int sum = 0;
#pragma unroll
    for (int j = 0; j < 8; ++j) { v[j] = (base + j < n) ? data[base + j] : 0; sum += v[j]; }
    s[t] = sum;
    __syncthreads();
    for (int off = 1; off < 256; off <<= 1) {
        int x = 0;
        if (t >= off) x = s[t - off];
        __syncthreads();
        s[t] += x;
        __syncthreads();
    }
    int run = s[t] - sum;
#pragma unroll
    for (int j = 0; j < 8; ++j) { if (base + j < n) data[base + j] = run; run += v[j]; }
    if (t == 255) blksum[blockIdx.x] = s[255];
}

__global__ void scanB_kernel(int* __restrict__ blksum, int nb) {
    __shared__ int s[256];
    int t = threadIdx.x;
    int v = (t < nb) ? blksum[t] : 0;
    s[t] = v;
    __syncthreads();
    for (int off = 1; off < 256; off <<= 1) {
        int x = 0;
        if (t >= off) x = s[t - off];
        __syncthreads();
        s[t] += x;
        __syncthreads();
    }
    if (t < nb) blksum[t] = s[t] - v;
}

__global__ void scanC_kernel(int* __restrict__ data, const int* __restrict__ blksum, int n) {
    int i = blockIdx.x * blockDim.x + threadIdx.x;
    if (i < n) data[i] += blksum[i >> 11];
}

// ---------------------------------------------------------------- norms (+ inverse)
__global__ void norms_kernel(const unsigned short* __restrict__ partial, const int* __restrict__ rp,
                             float* __restrict__ norm_src, float* __restrict__ inv_ns,
                             float* __restrict__ norm_dst) {
    int v = blockIdx.x * blockDim.x + threadIdx.x;
    if (v < N_NODES) {
        int d = 0;
#pragma unroll
        for (int s = 0; s < DH_SL; ++s) d += partial[(size_t)s * DH_PAD + v];
        float df = (float)max(d, 1);
        norm_src[v] = rsqrtf(df);
        inv_ns[v] = sqrtf(df);
        norm_dst[v] = rsqrtf((float)max(rp[v + 1] - rp[v], 1));
    }
}

// ---------------------------------------------------------------- weight prep (bf16, B^T, XOR-swizzled)
__global__ void wprep_kernel(const float* __restrict__ W, unsigned short* __restrict__ Wt) {
    int i = blockIdx.x * blockDim.x + threadIdx.x;
    if (i >= NLAYERS * D * D) return;
    int l = i >> 14;
    int r = i & (D * D - 1);
    int col = r >> 7;
    int k = r & 127;
    float v = W[(size_t)l * D * D + k * D + col];
    int byteoff = col * 256 + k * 2;
    int swz = byteoff ^ ((col & 7) << 4);
    Wt[(size_t)l * D * D + (swz >> 1)] = f2bf(v);
}

// ---------------------------------------------------------------- prep: P = bf16(h * norm_src)
__global__ __launch_bounds__(256) void prep_hs_kernel(const float* __restrict__ h,
                               const float* __restrict__ norm_src,
                               unsigned short* __restrict__ hs) {
    int tid = blockIdx.x * blockDim.x + threadIdx.x;
    int v = tid >> 4;
    if (v >= N_NODES) return;
    int c8 = (tid & 15) << 3;
    float ns = norm_src[v];
    float4 a = *reinterpret_cast<const float4*>(h + (size_t)v * D + c8);
    float4 b = *reinterpret_cast<const float4*>(h + (size_t)v * D + c8 + 4);
    unsigned short o[8] = {f2bf(a.x * ns), f2bf(a.y * ns), f2bf(a.z * ns), f2bf(a.w * ns),
                           f2bf(b.x * ns), f2bf(b.y * ns), f2bf(b.z * ns), f2bf(b.w * ns)};
    *reinterpret_cast<u16x8*>(hs + (size_t)v * D + c8) = *reinterpret_cast<u16x8*>(o);
}

// ---------------------------------------------------------------- aggregation (pre-scaled P, 8x MLP unroll)
__global__ __launch_bounds__(256) void agg_kernel(const unsigned short* __restrict__ hs,
                           const int* __restrict__ rp,
                           const int* __restrict__ col_idx, const float* __restrict__ norm_dst,
                           unsigned short* __restrict__ aggb) {
    int tid = blockIdx.x * blockDim.x + threadIdx.x;
    int v = tid >> 4;
    if (v >= N_NODES) return;
    int c8 = (tid & 15) << 3;
    int e0 = rp[v], e1 = rp[v + 1];
    float acc[8] = {0.f, 0.f, 0.f, 0.f, 0.f, 0.f, 0.f, 0.f};
    int e = e0;
    int e8 = e0 + ((e1 - e0) & ~7);
    for (; e < e8; e += 8) {
        int u[8];
#pragma unroll
        for (int q = 0; q < 8; ++q) u[q] = col_idx[e + q];
        u16x8 hv[8];
#pragma unroll
        for (int q = 0; q < 8; ++q)
            hv[q] = *reinterpret_cast<const u16x8*>(hs + (size_t)u[q] * D + c8);
#pragma unroll
        for (int j = 0; j < 8; ++j) {
            float s01 = bf2f(hv[0][j]) + bf2f(hv[1][j]);
            float s23 = bf2f(hv[2][j]) + bf2f(hv[3][j]);
            float s45 = bf2f(hv[4][j]) + bf2f(hv[5][j]);
            float s67 = bf2f(hv[6][j]) + bf2f(hv[7][j]);
            acc[j] += (s01 + s23) + (s45 + s67);
        }
    }
    for (; e < e1; ++e) {
        int u = col_idx[e];
        u16x8 hv = *reinterpret_cast<const u16x8*>(hs + (size_t)u * D + c8);
#pragma unroll
        for (int j = 0; j < 8; ++j) acc[j] += bf2f(hv[j]);
    }
    float nd = norm_dst[v];
    unsigned short o[8];
#pragma unroll
    for (int j = 0; j < 8; ++j) o[j] = f2bf(acc[j] * nd);
    *reinterpret_cast<u16x8*>(aggb + (size_t)v * D + c8) = *reinterpret_cast<u16x8*>(o);
}

// ---------------------------------------------------------------- MFMA GEMM (bf16 out) + per-block BN partials
__global__ __launch_bounds__(256) void gemm_mfma_kernel(const unsigned short* __restrict__ A,
        const unsigned short* __restrict__ Wt, const float* __restrict__ bl,
        unsigned short* __restrict__ outB, float* __restrict__ pstats, int nrows) {
    __shared__ __align__(16) unsigned char smem[33792];  // Wt stage (32KB) then C-transpose
    __shared__ float part[4 * 2 * 128];
    unsigned short* sW = reinterpret_cast<unsigned short*>(smem);
    int t = threadIdx.x;
#pragma unroll
    for (int i = 0; i < 8; ++i) {
        int idx = t + i * 256;
        reinterpret_cast<uint4*>(sW)[idx] = reinterpret_cast<const uint4*>(Wt)[idx];
    }
    __syncthreads();

    int wave = t >> 6;
    int lane = t & 63;
    int l15 = lane & 15;
    int lg = lane >> 4;
    int rowbase = blockIdx.x * 128 + wave * 32;

    f32x4 acc[2][8];
#pragma unroll
    for (int rf = 0; rf < 2; ++rf)
#pragma unroll
        for (int cf = 0; cf < 8; ++cf) acc[rf][cf] = (f32x4){0.f, 0.f, 0.f, 0.f};

    int rA[2];
#pragma unroll
    for (int rf = 0; rf < 2; ++rf) {
        int r = rowbase + rf * 16 + l15;
        rA[rf] = (r >= nrows) ? nrows - 1 : r;
    }

#pragma unroll
    for (int ks = 0; ks < 4; ++ks) {
        bf16x8 a[2];
#pragma unroll
        for (int rf = 0; rf < 2; ++rf)
            a[rf] = *reinterpret_cast<const bf16x8*>(A + (size_t)rA[rf] * D + ks * 32 + lg * 8);
#pragma unroll
        for (int cf = 0; cf < 8; ++cf) {
            int col = cf * 16 + l15;
            int byteoff = (col * 256 + ks * 64 + lg * 16) ^ ((col & 7) << 4);
            bf16x8 bfrag = *reinterpret_cast<const bf16x8*>(
                reinterpret_cast<const char*>(sW) + byteoff);
            acc[0][cf] = __builtin_amdgcn_mfma_f32_16x16x32_bf16(a[0], bfrag, acc[0][cf], 0, 0, 0);
            acc[1][cf] = __builtin_amdgcn_mfma_f32_16x16x32_bf16(a[1], bfrag, acc[1][cf], 0, 0, 0);
        }
    }

    __syncthreads();   // all waves done reading sW; reuse smem for C-transpose
    char* wbase = reinterpret_cast<char*>(smem) + wave * 8448;   // 32 rows x 264B

#pragma unroll
    for (int cf = 0; cf < 8; ++cf) {
        int c = cf * 16 + l15;
        float bias = bl[c];
        float s = 0.f, sq = 0.f;
#pragma unroll
        for (int rf = 0; rf < 2; ++rf) {
#pragma unroll
            for (int j = 0; j < 4; ++j) {
                int rl = rf * 16 + lg * 4 + j;
                float val = acc[rf][cf][j] + bias;
                *reinterpret_cast<unsigned short*>(wbase + rl * 264 + c * 2) = f2bf(val);
                if (rowbase + rl < nrows) { s += val; sq += val * val; }
            }
        }
        s += __shfl_xor(s, 16);
        s += __shfl_xor(s, 32);
        sq += __shfl_xor(sq, 16);
        sq += __shfl_xor(sq, 32);
        if (lg == 0) {
            part[wave * 256 + c] = s;
            part[wave * 256 + 128 + c] = sq;
        }
    }
    __syncthreads();
    float tot = part[0 * 256 + (t >> 7) * 128 + (t & 127)]
              + part[1 * 256 + (t >> 7) * 128 + (t & 127)]
              + part[2 * 256 + (t >> 7) * 128 + (t & 127)]
              + part[3 * 256 + (t >> 7) * 128 + (t & 127)];
    pstats[(size_t)blockIdx.x * 256 + t] = tot;

    int rl = lane >> 1;
    int colbase = (lane & 1) * 64;
    int grow = rowbase + rl;
    if (grow < nrows) {
#pragma unroll
        for (int k = 0; k < 8; ++k) {
            u16x8 vv = *reinterpret_cast<u16x8*>(wbase + rl * 264 + (colbase + k * 8) * 2);
            *reinterpret_cast<u16x8*>(outB + (size_t)grow * D + colbase + k * 8) = vv;
        }
    }
}

// ---------------------------------------------------------------- BN stat reduction + finalize
__global__ void reduce_pstats_kernel(const float* __restrict__ pstats, float* __restrict__ pstats2,
                                     int nblk) {
    int t = threadIdx.x;
    int bb = blockIdx.x;           // 16 blocks
    int chunk = (nblk + 15) / 16;
    int b0 = bb * chunk, b1 = min(b0 + chunk, nblk);
    float s = 0.f;
    for (int b = b0; b < b1; ++b) s += pstats[(size_t)b * 256 + t];
    pstats2[bb * 256 + t] = s;
}

__global__ void bn_finalize_kernel(const float* __restrict__ pstats2, const float* __restrict__ gamma,
                                   const float* __restrict__ beta, float* __restrict__ fin) {
    int c = threadIdx.x;   // 128
    float s = 0.f, sq = 0.f;
#pragma unroll
    for (int i = 0; i < 16; ++i) {
        s += pstats2[i * 256 + c];
        sq += pstats2[i * 256 + 128 + c];
    }
    float mu = s * (1.f / N_NODES);
    float var = sq * (1.f / N_NODES) - mu * mu;
    float sc = rsqrtf(var + BN_EPS) * gamma[c];
    fin[c] = sc;
    fin[D + c] = beta[c] - mu * sc;
}

// ---------------------------------------------------------------- BN apply (+relu,+residual)
// Residual reconstructed from P_prev: Xres = bf2f(Pres)*inv_ns[v].
// l<3: writes only P_out = bf16(o*ns). l==3 (last): writes only H = bf16(o).
__global__ __launch_bounds__(256) void bn_apply_kernel(const unsigned short* __restrict__ G,
                                const unsigned short* __restrict__ Pres,
                                const float* __restrict__ fin, const float* __restrict__ norm_src,
                                const float* __restrict__ inv_ns,
                                unsigned short* __restrict__ Wout,
                                int residual, int last) {
    int tid = blockIdx.x * blockDim.x + threadIdx.x;
    int v = tid >> 4;
    if (v >= N_NODES) return;
    int c8 = (tid & 15) << 3;
    u16x8 gv = *reinterpret_cast<const u16x8*>(G + (size_t)v * D + c8);
    float4 sc0 = *reinterpret_cast<const float4*>(fin + c8);
    float4 sc1 = *reinterpret_cast<const float4*>(fin + c8 + 4);
    float4 sh0 = *reinterpret_cast<const float4*>(fin + D + c8);
    float4 sh1 = *reinterpret_cast<const float4*>(fin + D + c8 + 4);
    float sc[8] = {sc0.x, sc0.y, sc0.z, sc0.w, sc1.x, sc1.y, sc1.z, sc1.w};
    float sh[8] = {sh0.x, sh0.y, sh0.z, sh0.w, sh1.x, sh1.y, sh1.z, sh1.w};
    float o[8];
#pragma unroll
    for (int j = 0; j < 8; ++j) o[j] = fmaxf(fmaf(bf2f(gv[j]), sc[j], sh[j]), 0.f);
    if (residual) {
        float iv = inv_ns[v];
        u16x8 xv = *reinterpret_cast<const u16x8*>(Pres + (size_t)v * D + c8);
#pragma unroll
        for (int j = 0; j < 8; ++j) o[j] = fmaf(bf2f(xv[j]), iv, o[j]);
    }
    unsigned short ob[8];
    if (last) {
#pragma unroll
        for (int j = 0; j < 8; ++j) ob[j] = f2bf(o[j]);
    } else {
        float ns = norm_src[v];
#pragma unroll
        for (int j = 0; j < 8; ++j) ob[j] = f2bf(o[j] * ns);
    }
    *reinterpret_cast<u16x8*>(Wout + (size_t)v * D + c8) = *reinterpret_cast<u16x8*>(ob);
}

// ---------------------------------------------------------------- pooling (bf16 in) + head
__global__ __launch_bounds__(256) void pool_kernel(const unsigned short* __restrict__ h,
                            const int* __restrict__ gid,
                            float* __restrict__ pooled) {
    int base = blockIdx.x * 1024;
    int c8 = (threadIdx.x & 15) << 3;
    int sub = threadIdx.x >> 4;
    int r0 = base + sub * 64;
    if (r0 >= N_NODES) return;
    int r1 = min(r0 + 64, N_NODES);
    int gcur = gid[r0];
    float a[8] = {0.f, 0.f, 0.f, 0.f, 0.f, 0.f, 0.f, 0.f};
    for (int row = r0; row < r1; ++row) {
        int g = gid[row];
        u16x8 hv = *reinterpret_cast<const u16x8*>(h + (size_t)row * D + c8);
        if (g != gcur) {
#pragma unroll
            for (int j = 0; j < 8; ++j) { atomicAdd(&pooled[gcur * D + c8 + j], a[j]); a[j] = 0.f; }
            gcur = g;
        }
#pragma unroll
        for (int j = 0; j < 8; ++j) a[j] += bf2f(hv[j]);
    }
#pragma unroll
    for (int j = 0; j < 8; ++j) atomicAdd(&pooled[gcur * D + c8 + j], a[j]);
}

__global__ void head_kernel(const float* __restrict__ pooled, const float* __restrict__ Wp,
                            const float* __restrict__ bp, float* __restrict__ out) {
    int tid = blockIdx.x * blockDim.x + threadIdx.x;
    if (tid >= NGRAPH * NOUT) return;
    int g = tid / NOUT, o = tid % NOUT;
    float sum = bp[o];
    for (int k = 0; k < D; ++k) sum = fmaf(pooled[g * D + k], Wp[k * NOUT + o], sum);
    out[tid] = sum;
}

// ----------------------------------------------------------------
extern "C" void kernel_launch(void* const* d_in, const int* in_sizes, int n_in,
                              void* d_out, int out_size, void* d_ws, size_t ws_size,
                              hipStream_t stream) {
    const float* h     = (const float*)d_in[0];
    const float* W     = (const float*)d_in[1];
    const float* b     = (const float*)d_in[2];
    const float* gamma = (const float*)d_in[3];
    const float* beta  = (const float*)d_in[4];
    const float* Wp    = (const float*)d_in[5];
    const float* bp    = (const float*)d_in[6];
    const int*   src   = (const int*)d_in[7];
    const int*   dst   = (const int*)d_in[8];
    const int*   gid   = (const int*)d_in[9];
    float* out = (float*)d_out;

    char* ws = (char*)d_ws;
    size_t off = 0;
    auto alloc = [&](size_t bytes) { char* p = ws + off; off = (off + bytes + 511) & ~(size_t)511; return p; };
    unsigned short* Pa  = (unsigned short*)alloc((size_t)N_NODES * D * 2);  // 25.6 MB
    unsigned short* Pb  = (unsigned short*)alloc((size_t)N_NODES * D * 2);  // 25.6 MB
    unsigned short* Gb  = (unsigned short*)alloc((size_t)N_NODES * D * 2);  // gemm out
    unsigned short* Q   = (unsigned short*)alloc((size_t)N_NODES * D * 2);  // agg out
    unsigned short* Wt  = (unsigned short*)alloc((size_t)NLAYERS * D * D * 2);
    unsigned short* partial = (unsigned short*)alloc((size_t)DH_SL * DH_PAD * 2);  // 7.3 MB
    int*   row_ptr  = (int*)alloc((size_t)(N_NODES + 1) * 4);
    int*   col_idx  = (int*)alloc((size_t)N_EDGES * 4);
    float* norm_src = (float*)alloc((size_t)N_NODES * 4);
    float* inv_ns   = (float*)alloc((size_t)N_NODES * 4);
    float* norm_dst = (float*)alloc((size_t)N_NODES * 4);
    int*   ph1      = (int*)alloc((size_t)512 * SORT_B * 4);
    int*   blksum   = (int*)alloc(256 * 4);
    float* pstats   = (float*)alloc((size_t)782 * 256 * 4);
    float* pstats2  = (float*)alloc((size_t)16 * 256 * 4);
    float* fin      = (float*)alloc(2 * D * 4);
    float* pooled   = (float*)alloc((size_t)NGRAPH * D * 4);

    // sort scratch aliased into Gb (dead until first gemm)
    int2* kv1 = (int2*)Gb;   // 12.8 MB <= 25.6 MB

    // ---- deg_out histogram (range-partitioned LDS, no global atomics)
    deg_hist_kernel<<<DH_NR * DH_SL, 256, 0, stream>>>(src, partial);

    // ---- pass 1: 512-bin bucket by dst>>8
    hist1_kernel<<<SORT_B, 256, 0, stream>>>(dst, ph1);
    int n1 = 512 * SORT_B;
    scanA_kernel<<<(n1 + 2047) / 2048, 256, 0, stream>>>(ph1, blksum, n1);
    scanB_kernel<<<1, 256, 0, stream>>>(blksum, (n1 + 2047) / 2048);
    scanC_kernel<<<(n1 + 255) / 256, 256, 0, stream>>>(ph1, blksum, n1);
    place1_kernel<<<SORT_B, 256, 0, stream>>>(dst, src, ph1, kv1);

    // ---- pass 2: in-LDS counting sort per bin -> col_idx + row_ptr
    binsort_kernel<<<SORT_B, 256, 0, stream>>>(kv1, ph1, col_idx, row_ptr);

    // ---- norms + weight/input prep
    norms_kernel<<<(N_NODES + 255) / 256, 256, 0, stream>>>(partial, row_ptr,
                                                            norm_src, inv_ns, norm_dst);
    wprep_kernel<<<(NLAYERS * D * D + 255) / 256, 256, 0, stream>>>(W, Wt);
    prep_hs_kernel<<<(N_NODES * 16 + 255) / 256, 256, 0, stream>>>(h, norm_src, Pa);

    // ---- layers: P ping-pong. rbuf holds P_{l-1} (agg input AND residual); wbuf gets P_l (or H_3).
    int gemm_blocks = (N_NODES + 127) / 128;   // 782
    for (int l = 0; l < NLAYERS; ++l) {
        unsigned short* rbuf = (l & 1) ? Pb : Pa;
        unsigned short* wbuf = (l & 1) ? Pa : Pb;
        agg_kernel<<<(N_NODES * 16 + 255) / 256, 256, 0, stream>>>(rbuf, row_ptr, col_idx,
                                                                   norm_dst, Q);
        gemm_mfma_kernel<<<gemm_blocks, 256, 0, stream>>>(Q, Wt + (size_t)l * D * D,
                                                          b + (size_t)l * D, Gb, pstats, N_NODES);
        reduce_pstats_kernel<<<16, 256, 0, stream>>>(pstats, pstats2, gemm_blocks);
        bn_finalize_kernel<<<1, 128, 0, stream>>>(pstats2, gamma + (size_t)l * D,
                                                  beta + (size_t)l * D, fin);
        bn_apply_kernel<<<(N_NODES * 16 + 255) / 256, 256, 0, stream>>>(
            Gb, rbuf, fin, norm_src, inv_ns, wbuf,
            l > 0 ? 1 : 0, l == NLAYERS - 1 ? 1 : 0);
    }

    // ---- pooling + head (H_3 in Pa after l=3 writes wbuf=Pa)
    hipMemsetAsync(pooled, 0, (size_t)NGRAPH * D * 4, stream);
    pool_kernel<<<(N_NODES + 1023) / 1024, 256, 0, stream>>>(Pa, gid, pooled);
    head_kernel<<<4, 256, 0, stream>>>(pooled, Wp, bp, out);
}